// Round 1
// baseline (621.260 us; speedup 1.0000x reference)
//
#include <hip/hip_runtime.h>
#include <hip/hip_bf16.h>

#define NN 50000
#define EE 600000
#define DD 128
#define RR 8
#define NSEG (NN*RR)                     // 400000
#define NB_SCAN ((NSEG + 1023)/1024)     // 391

typedef unsigned int u32;
typedef __attribute__((ext_vector_type(8))) short bf16x8;
typedef __attribute__((ext_vector_type(4))) float f32x4;

// fp32 -> bf16 round-to-nearest-even (finite inputs only)
__device__ inline unsigned short f2bf(float f){
  u32 u = __float_as_uint(f);
  u32 r = (u + 0x7fffu + ((u >> 16) & 1u)) >> 16;
  return (unsigned short)r;
}

// ---------------- conversion: fp32 -> bf16, 4 elems/thread ----------------
__global__ void cvt_k(const float* __restrict__ in, unsigned short* __restrict__ out, int n4){
  int i = blockIdx.x * 256 + threadIdx.x;
  if (i >= n4) return;
  float4 v = ((const float4*)in)[i];
  ushort4 o;
  o.x = f2bf(v.x); o.y = f2bf(v.y); o.z = f2bf(v.z); o.w = f2bf(v.w);
  ((ushort4*)out)[i] = o;
}

// ---------------- pack B (W stack) into MFMA fragment order ----------------
// frag id = k32*8 + nf; within frag: lane*8 + i
// element: B[k32*32 + (lane>>4)*8 + i][nf*16 + (lane&15)]
// B row kk: kk < krel -> Wrel[kk*128+col] (kk = r*128+d), else root[(kk-krel)*128+col]
__global__ void pack_k(const float* __restrict__ Wrel, const float* __restrict__ root,
                       short* __restrict__ Bp, int nk32, int krel){
  int tid = blockIdx.x * 256 + threadIdx.x;
  if (tid >= nk32 * 512) return;
  int lane = tid & 63;
  int nf   = (tid >> 6) & 7;
  int k32  = tid >> 9;
  int col  = nf * 16 + (lane & 15);
  short vals[8];
#pragma unroll
  for (int i = 0; i < 8; ++i){
    int kk = k32 * 32 + ((lane >> 4) << 3) + i;
    float f = (kk < krel) ? Wrel[(size_t)kk * 128 + col]
                          : root[(size_t)(kk - krel) * 128 + col];
    vals[i] = (short)f2bf(f);
  }
  *(bf16x8*)(Bp + (size_t)tid * 8) = *(const bf16x8*)vals;
}

// ---------------- CSR build ----------------
__global__ void count_k(const int* __restrict__ dst, const int* __restrict__ et,
                        u32* __restrict__ cnt){
  int e = blockIdx.x * 256 + threadIdx.x;
  if (e >= EE) return;
  atomicAdd(&cnt[(size_t)dst[e] * RR + et[e]], 1u);
}

__global__ void scan1_k(const u32* __restrict__ cnt, u32* __restrict__ offs, u32* __restrict__ bsum){
  __shared__ u32 s[512];
  int t = threadIdx.x;                       // 256 threads
  int base = blockIdx.x * 1024 + t * 4;
  u32 loc[4]; u32 sum = 0;
#pragma unroll
  for (int i = 0; i < 4; ++i){ loc[i] = (base + i < NSEG) ? cnt[base + i] : 0u; sum += loc[i]; }
  int pb = 0;
  s[t] = sum; __syncthreads();
  for (int off = 1; off < 256; off <<= 1){
    u32 v = s[pb * 256 + t];
    if (t >= off) v += s[pb * 256 + t - off];
    s[(pb ^ 1) * 256 + t] = v; pb ^= 1; __syncthreads();
  }
  u32 incl = s[pb * 256 + t];
  u32 excl = incl - sum;
  if (t == 255) bsum[blockIdx.x] = incl;
  u32 run = excl;
#pragma unroll
  for (int i = 0; i < 4; ++i){ if (base + i < NSEG) offs[base + i] = run; run += loc[i]; }
}

__global__ void scan2_k(u32* __restrict__ bsum){
  __shared__ u32 s[1024];
  int t = threadIdx.x;                       // 512 threads
  u32 v = (t < NB_SCAN) ? bsum[t] : 0u;
  int pb = 0;
  s[t] = v; __syncthreads();
  for (int off = 1; off < 512; off <<= 1){
    u32 x = s[pb * 512 + t];
    if (t >= off) x += s[pb * 512 + t - off];
    s[(pb ^ 1) * 512 + t] = x; pb ^= 1; __syncthreads();
  }
  u32 incl = s[pb * 512 + t];
  if (t < NB_SCAN) bsum[t] = incl - v;       // exclusive
}

__global__ void scan3_k(u32* __restrict__ offs, const u32* __restrict__ bsum){
  int t = threadIdx.x;
  int base = blockIdx.x * 1024 + t * 4;
  u32 add = bsum[blockIdx.x];
#pragma unroll
  for (int i = 0; i < 4; ++i){ if (base + i < NSEG) offs[base + i] += add; }
  if (blockIdx.x == 0 && t == 0) offs[NSEG] = EE;
}

__global__ void fill_k(const int* __restrict__ src, const int* __restrict__ dst,
                       const int* __restrict__ et, const u32* __restrict__ offs,
                       u32* __restrict__ cur, int* __restrict__ ssrc){
  int e = blockIdx.x * 256 + threadIdx.x;
  if (e >= EE) return;
  int s = dst[e] * RR + et[e];
  u32 p = atomicAdd(&cur[s], 1u);
  ssrc[offs[s] + p] = src[e];
}

// ---------------- per-(relation,dst) mean aggregation -> a[N, R*D] bf16 ----
__global__ void agg_k(const u32* __restrict__ offs, const int* __restrict__ ssrc,
                      const unsigned short* __restrict__ hbf, unsigned short* __restrict__ a){
  int seg = blockIdx.x * 4 + (threadIdx.x >> 6);
  int l = threadIdx.x & 63;
  u32 beg = offs[seg], end = offs[seg + 1];
  float sx = 0.f, sy = 0.f;
  for (u32 e = beg; e < end; ++e){
    int sv = ssrc[e];
    u32 pv = *(const u32*)(hbf + (size_t)sv * 128 + l * 2);
    sx += __uint_as_float(pv << 16);
    sy += __uint_as_float(pv & 0xffff0000u);
  }
  if (end > beg){ float inv = 1.f / (float)(end - beg); sx *= inv; sy *= inv; }
  u32 o = (u32)f2bf(sx) | ((u32)f2bf(sy) << 16);
  *(u32*)(a + (size_t)seg * 128 + l * 2) = o;
}

// ---------------- MFMA GEMM: out[v,:] = [a_row | h_row] @ Bpack + bias ----
// OUTMODE 0: outf = acc + bias                       (res projection)
// OUTMODE 1: outb = bf16(res + relu(acc + bias))     (layers 1,2)
// OUTMODE 2: outf = res + relu(acc + bias)           (layer 3 -> d_out)
#define GLD16(g, l)  __builtin_amdgcn_global_load_lds( \
    (const __attribute__((address_space(1))) void*)(g), \
    (__attribute__((address_space(3))) void*)(l), 16, 0, 0)

template<int KTA, int KTH, int OUTMODE>
__launch_bounds__(256, 2)
__global__ void gemm_k(const unsigned short* __restrict__ Aa,   // [N,1024] bf16 (agg), may be null
                       const unsigned short* __restrict__ Ah,   // [N,128]  bf16 (h)
                       const short* __restrict__ Bp,            // packed fragments
                       const float* __restrict__ bias,
                       const float* __restrict__ res,
                       float* __restrict__ outf,
                       unsigned short* __restrict__ outb){
  __shared__ short Alds[128 * 64];          // 16 KB, BM=128 x BK=64 bf16, col8-XOR swizzled
  const int tid = threadIdx.x;
  const int w = tid >> 6, l = tid & 63;
  const int mbase = blockIdx.x * 128;
  f32x4 acc[2][8] = {};

#pragma unroll 1
  for (int kt = 0; kt < KTA + KTH; ++kt){
    const unsigned short* srcb; int rs, ko;
    if (kt < KTA){ srcb = Aa; rs = 1024; ko = kt * 64; }
    else         { srcb = Ah; rs = 128;  ko = (kt - KTA) * 64; }
    // stage A tile [128][64] bf16; LDS linear, source column pre-swizzled
#pragma unroll
    for (int i = 0; i < 4; ++i){
      int c = i * 256 + w * 64 + l;         // 16B chunk id
      int row = c >> 3, p = c & 7;
      int grow = mbase + row; if (grow > NN - 1) grow = NN - 1;
      const unsigned short* g = srcb + (size_t)grow * rs + ko + ((p ^ (row & 7)) << 3);
      GLD16(g, Alds + (size_t)(i * 256 + w * 64) * 8);
    }
    __syncthreads();
#pragma unroll
    for (int t = 0; t < 2; ++t){
      bf16x8 af[2];
#pragma unroll
      for (int mf = 0; mf < 2; ++mf){
        int row = w * 32 + mf * 16 + (l & 15);
        int p = (t * 4 + (l >> 4)) ^ (row & 7);
        af[mf] = *(const bf16x8*)(Alds + row * 64 + p * 8);
      }
      const short* bb = Bp + (size_t)((kt * 2 + t) * 8) * 512 + l * 8;
#pragma unroll
      for (int nf = 0; nf < 8; ++nf){
        bf16x8 bq = *(const bf16x8*)(bb + nf * 512);
        acc[0][nf] = __builtin_amdgcn_mfma_f32_16x16x32_bf16(af[0], bq, acc[0][nf], 0, 0, 0);
        acc[1][nf] = __builtin_amdgcn_mfma_f32_16x16x32_bf16(af[1], bq, acc[1][nf], 0, 0, 0);
      }
    }
    __syncthreads();
  }

  const int lr = l >> 4, lc = l & 15;
#pragma unroll
  for (int mf = 0; mf < 2; ++mf){
#pragma unroll
    for (int nf = 0; nf < 8; ++nf){
      int col = nf * 16 + lc;
      float bv = bias[col];
#pragma unroll
      for (int r = 0; r < 4; ++r){
        int row = mbase + w * 32 + mf * 16 + lr * 4 + r;
        if (row < NN){
          float v = acc[mf][nf][r] + bv;
          if (OUTMODE >= 1) v = res[(size_t)row * 128 + col] + fmaxf(v, 0.f);
          if (OUTMODE == 1) outb[(size_t)row * 128 + col] = f2bf(v);
          else              outf[(size_t)row * 128 + col] = v;
        }
      }
    }
  }
}

extern "C" void kernel_launch(void* const* d_in, const int* in_sizes, int n_in,
                              void* d_out, int out_size, void* d_ws, size_t ws_size,
                              hipStream_t stream){
  const float* x  = (const float*)d_in[0];
  const int*   ei = (const int*)d_in[1];
  const int*   et = (const int*)d_in[2];
  const float* W1 = (const float*)d_in[3];
  const float* r1 = (const float*)d_in[4];
  const float* b1 = (const float*)d_in[5];
  const float* W2 = (const float*)d_in[6];
  const float* r2 = (const float*)d_in[7];
  const float* b2 = (const float*)d_in[8];
  const float* W3 = (const float*)d_in[9];
  const float* r3 = (const float*)d_in[10];
  const float* b3 = (const float*)d_in[11];
  const float* rw = (const float*)d_in[12];
  const float* rb = (const float*)d_in[13];
  const int* srcv = ei;
  const int* dstv = ei + EE;

  char* p = (char*)d_ws;
  auto take = [&](size_t b)->char*{ char* q = p; p += (b + 255) & ~(size_t)255; return q; };
  unsigned short* a    = (unsigned short*)take((size_t)NN * 1024 * 2);  // 102.4 MB
  unsigned short* xb   = (unsigned short*)take((size_t)NN * 128 * 2);
  unsigned short* h1   = (unsigned short*)take((size_t)NN * 128 * 2);
  unsigned short* h2   = (unsigned short*)take((size_t)NN * 128 * 2);
  float*          resb = (float*)take((size_t)NN * 128 * 4);
  short* Bp1 = (short*)take(36 * 4096 * 2);
  short* Bp2 = (short*)take(36 * 4096 * 2);
  short* Bp3 = (short*)take(36 * 4096 * 2);
  short* BpR = (short*)take(4 * 4096 * 2);
  u32* cnt  = (u32*)take((size_t)NSEG * 4);
  u32* offs = (u32*)take((size_t)(NSEG + 1) * 4);
  u32* cur  = (u32*)take((size_t)NSEG * 4);
  int* ssrc = (int*)take((size_t)EE * 4);
  u32* bsum = (u32*)take((size_t)NB_SCAN * 4);

  hipMemsetAsync(cnt, 0, (size_t)NSEG * 4, stream);
  hipMemsetAsync(cur, 0, (size_t)NSEG * 4, stream);

  // conversions + weight packing (once)
  cvt_k<<<(NN * 128 / 4 + 255) / 256, 256, 0, stream>>>(x, xb, NN * 128 / 4);
  pack_k<<<(36 * 512 + 255) / 256, 256, 0, stream>>>(W1, r1, Bp1, 36, 1024);
  pack_k<<<(36 * 512 + 255) / 256, 256, 0, stream>>>(W2, r2, Bp2, 36, 1024);
  pack_k<<<(36 * 512 + 255) / 256, 256, 0, stream>>>(W3, r3, Bp3, 36, 1024);
  pack_k<<<(4 * 512 + 255) / 256, 256, 0, stream>>>(nullptr, rw, BpR, 4, 0);

  // CSR over segments (dst*R + etype), once for all layers
  count_k<<<(EE + 255) / 256, 256, 0, stream>>>(dstv, et, cnt);
  scan1_k<<<NB_SCAN, 256, 0, stream>>>(cnt, offs, bsum);
  scan2_k<<<1, 512, 0, stream>>>(bsum);
  scan3_k<<<NB_SCAN, 256, 0, stream>>>(offs, bsum);
  fill_k<<<(EE + 255) / 256, 256, 0, stream>>>(srcv, dstv, et, offs, cur, ssrc);

  const int GB = (NN + 127) / 128;  // 391

  // res = x @ res_w + res_b
  gemm_k<0, 2, 0><<<GB, 256, 0, stream>>>(nullptr, xb, BpR, rb, nullptr, resb, nullptr);

  // layer 1
  agg_k<<<NSEG / 4, 256, 0, stream>>>(offs, ssrc, xb, a);
  gemm_k<16, 2, 1><<<GB, 256, 0, stream>>>(a, xb, Bp1, b1, resb, nullptr, h1);
  // layer 2
  agg_k<<<NSEG / 4, 256, 0, stream>>>(offs, ssrc, h1, a);
  gemm_k<16, 2, 1><<<GB, 256, 0, stream>>>(a, h1, Bp2, b2, resb, nullptr, h2);
  // layer 3
  agg_k<<<NSEG / 4, 256, 0, stream>>>(offs, ssrc, h2, a);
  gemm_k<16, 2, 2><<<GB, 256, 0, stream>>>(a, h2, Bp3, b3, resb, (float*)d_out, nullptr);
}

// Round 2
// 411.032 us; speedup vs baseline: 1.5115x; 1.5115x over previous
//
#include <hip/hip_runtime.h>
#include <hip/hip_bf16.h>

#define NN 50000
#define EE 600000
#define DD 128
#define RR 8
#define NSEG (NN*RR)                     // 400000
#define NB_SCAN ((NSEG + 1023)/1024)     // 391

typedef unsigned int u32;
typedef __attribute__((ext_vector_type(8))) short bf16x8;
typedef __attribute__((ext_vector_type(4))) float f32x4;
typedef __attribute__((ext_vector_type(4))) u32 u32x4;

// fp32 -> bf16 round-to-nearest-even (finite inputs only)
__device__ inline unsigned short f2bf(float f){
  u32 u = __float_as_uint(f);
  u32 r = (u + 0x7fffu + ((u >> 16) & 1u)) >> 16;
  return (unsigned short)r;
}

// ---------------- conversion: fp32 -> bf16, 4 elems/thread ----------------
__global__ void cvt_k(const float* __restrict__ in, unsigned short* __restrict__ out, int n4){
  int i = blockIdx.x * 256 + threadIdx.x;
  if (i >= n4) return;
  float4 v = ((const float4*)in)[i];
  ushort4 o;
  o.x = f2bf(v.x); o.y = f2bf(v.y); o.z = f2bf(v.z); o.w = f2bf(v.w);
  ((ushort4*)out)[i] = o;
}

// ---------------- pack B (W stack) into MFMA fragment order ----------------
__global__ void pack_k(const float* __restrict__ Wrel, const float* __restrict__ root,
                       short* __restrict__ Bp, int nk32, int krel){
  int tid = blockIdx.x * 256 + threadIdx.x;
  if (tid >= nk32 * 512) return;
  int lane = tid & 63;
  int nf   = (tid >> 6) & 7;
  int k32  = tid >> 9;
  int col  = nf * 16 + (lane & 15);
  short vals[8];
#pragma unroll
  for (int i = 0; i < 8; ++i){
    int kk = k32 * 32 + ((lane >> 4) << 3) + i;
    float f = (kk < krel) ? Wrel[(size_t)kk * 128 + col]
                          : root[(size_t)(kk - krel) * 128 + col];
    vals[i] = (short)f2bf(f);
  }
  *(bf16x8*)(Bp + (size_t)tid * 8) = *(const bf16x8*)vals;
}

// ---------------- CSR build ----------------
__global__ void count_k(const int* __restrict__ dst, const int* __restrict__ et,
                        u32* __restrict__ cnt){
  int e = blockIdx.x * 256 + threadIdx.x;
  if (e >= EE) return;
  atomicAdd(&cnt[(size_t)dst[e] * RR + et[e]], 1u);
}

__global__ void scan1_k(const u32* __restrict__ cnt, u32* __restrict__ offs, u32* __restrict__ bsum){
  __shared__ u32 s[512];
  int t = threadIdx.x;                       // 256 threads
  int base = blockIdx.x * 1024 + t * 4;
  u32 loc[4]; u32 sum = 0;
#pragma unroll
  for (int i = 0; i < 4; ++i){ loc[i] = (base + i < NSEG) ? cnt[base + i] : 0u; sum += loc[i]; }
  int pb = 0;
  s[t] = sum; __syncthreads();
  for (int off = 1; off < 256; off <<= 1){
    u32 v = s[pb * 256 + t];
    if (t >= off) v += s[pb * 256 + t - off];
    s[(pb ^ 1) * 256 + t] = v; pb ^= 1; __syncthreads();
  }
  u32 incl = s[pb * 256 + t];
  u32 excl = incl - sum;
  if (t == 255) bsum[blockIdx.x] = incl;
  u32 run = excl;
#pragma unroll
  for (int i = 0; i < 4; ++i){ if (base + i < NSEG) offs[base + i] = run; run += loc[i]; }
}

__global__ void scan2_k(u32* __restrict__ bsum){
  __shared__ u32 s[1024];
  int t = threadIdx.x;                       // 512 threads
  u32 v = (t < NB_SCAN) ? bsum[t] : 0u;
  int pb = 0;
  s[t] = v; __syncthreads();
  for (int off = 1; off < 512; off <<= 1){
    u32 x = s[pb * 512 + t];
    if (t >= off) x += s[pb * 512 + t - off];
    s[(pb ^ 1) * 512 + t] = x; pb ^= 1; __syncthreads();
  }
  u32 incl = s[pb * 512 + t];
  if (t < NB_SCAN) bsum[t] = incl - v;       // exclusive
}

__global__ void scan3_k(u32* __restrict__ offs, const u32* __restrict__ bsum){
  int t = threadIdx.x;
  int base = blockIdx.x * 1024 + t * 4;
  u32 add = bsum[blockIdx.x];
#pragma unroll
  for (int i = 0; i < 4; ++i){ if (base + i < NSEG) offs[base + i] += add; }
  if (blockIdx.x == 0 && t == 0) offs[NSEG] = EE;
}

__global__ void fill_k(const int* __restrict__ src, const int* __restrict__ dst,
                       const int* __restrict__ et, const u32* __restrict__ offs,
                       u32* __restrict__ cur, int* __restrict__ ssrc){
  int e = blockIdx.x * 256 + threadIdx.x;
  if (e >= EE) return;
  int s = dst[e] * RR + et[e];
  u32 p = atomicAdd(&cur[s], 1u);
  ssrc[offs[s] + p] = src[e];
}

// ------- per-(relation,dst) mean aggregation -> a[N, R*D] bf16 ----------
// 4 segments per wave: 16-lane group per segment, each lane owns 8 channels
// (16B loads). 4 independent load chains per wave -> 4x MLP vs 1-seg/wave.
__global__ void agg_k(const u32* __restrict__ offs, const int* __restrict__ ssrc,
                      const unsigned short* __restrict__ hbf, unsigned short* __restrict__ a){
  int t = threadIdx.x;
  int wid = t >> 6, l = t & 63;
  int sub = l >> 4, ll = l & 15;
  int seg = blockIdx.x * 16 + wid * 4 + sub;
  u32 beg = offs[seg], end = offs[seg + 1];
  float s[8] = {0.f,0.f,0.f,0.f,0.f,0.f,0.f,0.f};
  const unsigned short* hb = hbf + (size_t)ll * 8;
  u32 e = beg;
  for (; e + 2 <= end; e += 2){
    int sv0 = ssrc[e], sv1 = ssrc[e + 1];
    u32x4 p0 = *(const u32x4*)(hb + (size_t)sv0 * 128);
    u32x4 p1 = *(const u32x4*)(hb + (size_t)sv1 * 128);
#pragma unroll
    for (int i = 0; i < 4; ++i){
      s[2*i]   += __uint_as_float(p0[i] << 16)        + __uint_as_float(p1[i] << 16);
      s[2*i+1] += __uint_as_float(p0[i] & 0xffff0000u) + __uint_as_float(p1[i] & 0xffff0000u);
    }
  }
  if (e < end){
    int sv0 = ssrc[e];
    u32x4 p0 = *(const u32x4*)(hb + (size_t)sv0 * 128);
#pragma unroll
    for (int i = 0; i < 4; ++i){
      s[2*i]   += __uint_as_float(p0[i] << 16);
      s[2*i+1] += __uint_as_float(p0[i] & 0xffff0000u);
    }
  }
  u32 deg = end - beg;
  if (deg){
    float inv = 1.f / (float)deg;
#pragma unroll
    for (int i = 0; i < 8; ++i) s[i] *= inv;
  }
  u32x4 o;
#pragma unroll
  for (int i = 0; i < 4; ++i)
    o[i] = (u32)f2bf(s[2*i]) | ((u32)f2bf(s[2*i+1]) << 16);
  *(u32x4*)(a + (size_t)seg * 128 + ll * 8) = o;
}

// ---------------- MFMA GEMM: out[v,:] = [a_row | h_row] @ Bpack + bias ----
// BM=64 (1 wave owns 16 rows), BK=64. 782 blocks -> ~3 blocks/CU.
// OUTMODE 0: outf = acc + bias
// OUTMODE 1: outb = bf16(res + relu(acc + bias))
// OUTMODE 2: outf = res + relu(acc + bias)
#define GLD16(g, l)  __builtin_amdgcn_global_load_lds( \
    (const __attribute__((address_space(1))) void*)(g), \
    (__attribute__((address_space(3))) void*)(l), 16, 0, 0)

template<int KTA, int KTH, int OUTMODE>
__launch_bounds__(256, 4)
__global__ void gemm_k(const unsigned short* __restrict__ Aa,   // [N,1024] bf16 (agg), may be null
                       const unsigned short* __restrict__ Ah,   // [N,128]  bf16 (h)
                       const short* __restrict__ Bp,            // packed fragments
                       const float* __restrict__ bias,
                       const float* __restrict__ res,
                       float* __restrict__ outf,
                       unsigned short* __restrict__ outb){
  __shared__ short Alds[64 * 64];           // 8 KB, BM=64 x BK=64, col8-XOR swizzled
  const int tid = threadIdx.x;
  const int w = tid >> 6, l = tid & 63;
  const int mbase = blockIdx.x * 64;
  f32x4 acc[8] = {};

#pragma unroll 1
  for (int kt = 0; kt < KTA + KTH; ++kt){
    const unsigned short* srcb; int rs, ko;
    if (kt < KTA){ srcb = Aa; rs = 1024; ko = kt * 64; }
    else         { srcb = Ah; rs = 128;  ko = (kt - KTA) * 64; }
    // stage A tile [64][64] bf16; LDS linear, source column pre-swizzled
#pragma unroll
    for (int i = 0; i < 2; ++i){
      int c = i * 256 + w * 64 + l;         // 16B chunk id
      int row = c >> 3, p = c & 7;
      int grow = mbase + row; if (grow > NN - 1) grow = NN - 1;
      const unsigned short* g = srcb + (size_t)grow * rs + ko + ((p ^ (row & 7)) << 3);
      GLD16(g, Alds + (size_t)(i * 256 + w * 64) * 8);
    }
    __syncthreads();
#pragma unroll
    for (int t = 0; t < 2; ++t){
      int row = w * 16 + (l & 15);
      int p = (t * 4 + (l >> 4)) ^ (row & 7);
      bf16x8 af = *(const bf16x8*)(Alds + row * 64 + p * 8);
      const short* bb = Bp + (size_t)((kt * 2 + t) * 8) * 512 + l * 8;
#pragma unroll
      for (int nf = 0; nf < 8; ++nf){
        bf16x8 bq = *(const bf16x8*)(bb + nf * 512);
        acc[nf] = __builtin_amdgcn_mfma_f32_16x16x32_bf16(af, bq, acc[nf], 0, 0, 0);
      }
    }
    __syncthreads();
  }

  const int lr = l >> 4, lc = l & 15;
#pragma unroll
  for (int nf = 0; nf < 8; ++nf){
    int col = nf * 16 + lc;
    float bv = bias[col];
#pragma unroll
    for (int r = 0; r < 4; ++r){
      int row = mbase + w * 16 + lr * 4 + r;
      if (row < NN){
        float v = acc[nf][r] + bv;
        if (OUTMODE >= 1) v = res[(size_t)row * 128 + col] + fmaxf(v, 0.f);
        if (OUTMODE == 1) outb[(size_t)row * 128 + col] = f2bf(v);
        else              outf[(size_t)row * 128 + col] = v;
      }
    }
  }
}

extern "C" void kernel_launch(void* const* d_in, const int* in_sizes, int n_in,
                              void* d_out, int out_size, void* d_ws, size_t ws_size,
                              hipStream_t stream){
  const float* x  = (const float*)d_in[0];
  const int*   ei = (const int*)d_in[1];
  const int*   et = (const int*)d_in[2];
  const float* W1 = (const float*)d_in[3];
  const float* r1 = (const float*)d_in[4];
  const float* b1 = (const float*)d_in[5];
  const float* W2 = (const float*)d_in[6];
  const float* r2 = (const float*)d_in[7];
  const float* b2 = (const float*)d_in[8];
  const float* W3 = (const float*)d_in[9];
  const float* r3 = (const float*)d_in[10];
  const float* b3 = (const float*)d_in[11];
  const float* rw = (const float*)d_in[12];
  const float* rb = (const float*)d_in[13];
  const int* srcv = ei;
  const int* dstv = ei + EE;

  char* p = (char*)d_ws;
  auto take = [&](size_t b)->char*{ char* q = p; p += (b + 255) & ~(size_t)255; return q; };
  unsigned short* a    = (unsigned short*)take((size_t)NN * 1024 * 2);  // 102.4 MB
  unsigned short* xb   = (unsigned short*)take((size_t)NN * 128 * 2);
  unsigned short* h1   = (unsigned short*)take((size_t)NN * 128 * 2);
  unsigned short* h2   = (unsigned short*)take((size_t)NN * 128 * 2);
  float*          resb = (float*)take((size_t)NN * 128 * 4);
  short* Bp1 = (short*)take(36 * 4096 * 2);
  short* Bp2 = (short*)take(36 * 4096 * 2);
  short* Bp3 = (short*)take(36 * 4096 * 2);
  short* BpR = (short*)take(4 * 4096 * 2);
  u32* cnt  = (u32*)take((size_t)NSEG * 4);
  u32* offs = (u32*)take((size_t)(NSEG + 1) * 4);
  u32* cur  = (u32*)take((size_t)NSEG * 4);
  int* ssrc = (int*)take((size_t)EE * 4);
  u32* bsum = (u32*)take((size_t)NB_SCAN * 4);

  hipMemsetAsync(cnt, 0, (size_t)NSEG * 4, stream);
  hipMemsetAsync(cur, 0, (size_t)NSEG * 4, stream);

  // conversions + weight packing (once)
  cvt_k<<<(NN * 128 / 4 + 255) / 256, 256, 0, stream>>>(x, xb, NN * 128 / 4);
  pack_k<<<(36 * 512 + 255) / 256, 256, 0, stream>>>(W1, r1, Bp1, 36, 1024);
  pack_k<<<(36 * 512 + 255) / 256, 256, 0, stream>>>(W2, r2, Bp2, 36, 1024);
  pack_k<<<(36 * 512 + 255) / 256, 256, 0, stream>>>(W3, r3, Bp3, 36, 1024);
  pack_k<<<(4 * 512 + 255) / 256, 256, 0, stream>>>(nullptr, rw, BpR, 4, 0);

  // CSR over segments (dst*R + etype), once for all layers
  count_k<<<(EE + 255) / 256, 256, 0, stream>>>(dstv, et, cnt);
  scan1_k<<<NB_SCAN, 256, 0, stream>>>(cnt, offs, bsum);
  scan2_k<<<1, 512, 0, stream>>>(bsum);
  scan3_k<<<NB_SCAN, 256, 0, stream>>>(offs, bsum);
  fill_k<<<(EE + 255) / 256, 256, 0, stream>>>(srcv, dstv, et, offs, cur, ssrc);

  const int GB = (NN + 63) / 64;  // 782

  // res = x @ res_w + res_b
  gemm_k<0, 2, 0><<<GB, 256, 0, stream>>>(nullptr, xb, BpR, rb, nullptr, resb, nullptr);

  // layer 1
  agg_k<<<NSEG / 16, 256, 0, stream>>>(offs, ssrc, xb, a);
  gemm_k<16, 2, 1><<<GB, 256, 0, stream>>>(a, xb, Bp1, b1, resb, nullptr, h1);
  // layer 2
  agg_k<<<NSEG / 16, 256, 0, stream>>>(offs, ssrc, h1, a);
  gemm_k<16, 2, 1><<<GB, 256, 0, stream>>>(a, h1, Bp2, b2, resb, nullptr, h2);
  // layer 3
  agg_k<<<NSEG / 16, 256, 0, stream>>>(offs, ssrc, h2, a);
  gemm_k<16, 2, 2><<<GB, 256, 0, stream>>>(a, h2, Bp3, b3, resb, (float*)d_out, nullptr);
}

// Round 3
// 402.218 us; speedup vs baseline: 1.5446x; 1.0219x over previous
//
#include <hip/hip_runtime.h>
#include <hip/hip_bf16.h>

#define NN 50000
#define EE 600000
#define RR 8
#define NSEG (NN*RR)                     // 400000
#define NB_SCAN ((NSEG + 1023)/1024)     // 391

typedef unsigned int u32;
typedef __attribute__((ext_vector_type(8))) short bf16x8;
typedef __attribute__((ext_vector_type(4))) float f32x4;
typedef __attribute__((ext_vector_type(4))) u32 u32x4;

// fp32 -> bf16 round-to-nearest-even (finite inputs only)
__device__ inline unsigned short f2bf(float f){
  u32 u = __float_as_uint(f);
  u32 r = (u + 0x7fffu + ((u >> 16) & 1u)) >> 16;
  return (unsigned short)r;
}
__device__ inline float bf2f(unsigned short b){ return __uint_as_float((u32)b << 16); }

// Wave-level LDS fence: drain ds ops, forbid compiler motion across (rule #18).
#define WAVE_FENCE() do{ __builtin_amdgcn_sched_barrier(0); \
  asm volatile("s_waitcnt lgkmcnt(0)" ::: "memory"); \
  __builtin_amdgcn_sched_barrier(0); }while(0)

// ---------------- conversion: fp32 -> bf16, 4 elems/thread ----------------
__global__ void cvt_k(const float* __restrict__ in, unsigned short* __restrict__ out, int n4){
  int i = blockIdx.x * 256 + threadIdx.x;
  if (i >= n4) return;
  float4 v = ((const float4*)in)[i];
  ushort4 o;
  o.x = f2bf(v.x); o.y = f2bf(v.y); o.z = f2bf(v.z); o.w = f2bf(v.w);
  ((ushort4*)out)[i] = o;
}

// ---------------- pack B (W stack) into MFMA fragment order ----------------
// frag id = k32*8 + nf; within frag: lane*8 + i
// element: B[k32*32 + (lane>>4)*8 + i][nf*16 + (lane&15)]
__global__ void pack_k(const float* __restrict__ Wrel, const float* __restrict__ root,
                       short* __restrict__ Bp, int nk32, int krel){
  int tid = blockIdx.x * 256 + threadIdx.x;
  if (tid >= nk32 * 512) return;
  int lane = tid & 63;
  int nf   = (tid >> 6) & 7;
  int k32  = tid >> 9;
  int col  = nf * 16 + (lane & 15);
  short vals[8];
#pragma unroll
  for (int i = 0; i < 8; ++i){
    int kk = k32 * 32 + ((lane >> 4) << 3) + i;
    float f = (kk < krel) ? Wrel[(size_t)kk * 128 + col]
                          : root[(size_t)(kk - krel) * 128 + col];
    vals[i] = (short)f2bf(f);
  }
  *(bf16x8*)(Bp + (size_t)tid * 8) = *(const bf16x8*)vals;
}

// ---------------- CSR build (relation-major: seg = r*NN + dst) -------------
__global__ void count_k(const int* __restrict__ dst, const int* __restrict__ et,
                        u32* __restrict__ cnt){
  int e = blockIdx.x * 256 + threadIdx.x;
  if (e >= EE) return;
  atomicAdd(&cnt[(size_t)et[e] * NN + dst[e]], 1u);
}

__global__ void scan1_k(const u32* __restrict__ cnt, u32* __restrict__ offs, u32* __restrict__ bsum){
  __shared__ u32 s[512];
  int t = threadIdx.x;                       // 256 threads
  int base = blockIdx.x * 1024 + t * 4;
  u32 loc[4]; u32 sum = 0;
#pragma unroll
  for (int i = 0; i < 4; ++i){ loc[i] = (base + i < NSEG) ? cnt[base + i] : 0u; sum += loc[i]; }
  int pb = 0;
  s[t] = sum; __syncthreads();
  for (int off = 1; off < 256; off <<= 1){
    u32 v = s[pb * 256 + t];
    if (t >= off) v += s[pb * 256 + t - off];
    s[(pb ^ 1) * 256 + t] = v; pb ^= 1; __syncthreads();
  }
  u32 incl = s[pb * 256 + t];
  u32 excl = incl - sum;
  if (t == 255) bsum[blockIdx.x] = incl;
  u32 run = excl;
#pragma unroll
  for (int i = 0; i < 4; ++i){ if (base + i < NSEG) offs[base + i] = run; run += loc[i]; }
}

__global__ void scan2_k(u32* __restrict__ bsum){
  __shared__ u32 s[1024];
  int t = threadIdx.x;                       // 512 threads
  u32 v = (t < NB_SCAN) ? bsum[t] : 0u;
  int pb = 0;
  s[t] = v; __syncthreads();
  for (int off = 1; off < 512; off <<= 1){
    u32 x = s[pb * 512 + t];
    if (t >= off) x += s[pb * 512 + t - off];
    s[(pb ^ 1) * 512 + t] = x; pb ^= 1; __syncthreads();
  }
  u32 incl = s[pb * 512 + t];
  if (t < NB_SCAN) bsum[t] = incl - v;       // exclusive
}

__global__ void scan3_k(u32* __restrict__ offs, const u32* __restrict__ bsum){
  int t = threadIdx.x;
  int base = blockIdx.x * 1024 + t * 4;
  u32 add = bsum[blockIdx.x];
#pragma unroll
  for (int i = 0; i < 4; ++i){ if (base + i < NSEG) offs[base + i] += add; }
  if (blockIdx.x == 0 && t == 0) offs[NSEG] = EE;
}

__global__ void fill_k(const int* __restrict__ src, const int* __restrict__ dst,
                       const int* __restrict__ et, const u32* __restrict__ offs,
                       u32* __restrict__ cur, int* __restrict__ ssrc){
  int e = blockIdx.x * 256 + threadIdx.x;
  if (e >= EE) return;
  int s = et[e] * NN + dst[e];
  u32 p = atomicAdd(&cur[s], 1u);
  ssrc[offs[s] + p] = src[e];
}

// ---------------- res projection: resb = bf16(x @ res_w + res_b) ----------
__launch_bounds__(256, 4)
__global__ void resg_k(const unsigned short* __restrict__ xb, const short* __restrict__ Bp,
                       const float* __restrict__ rb, unsigned short* __restrict__ resb){
  __shared__ short Alds[64 * 128];
  const int tid = threadIdx.x;
  const int w = tid >> 6, l = tid & 63;
  const int sub = l >> 4, ll = l & 15;
  const int mbase = blockIdx.x * 64;
  short* Aw = Alds + w * 16 * 128;
  f32x4 acc[8] = {};

#pragma unroll
  for (int j = 0; j < 4; ++j){
    int rloc = j * 4 + sub;
    int v = mbase + w * 16 + rloc; if (v > NN - 1) v = NN - 1;
    u32x4 p = *(const u32x4*)(xb + (size_t)v * 128 + ll * 8);
    *(u32x4*)(Aw + rloc * 128 + ((ll ^ rloc) << 3)) = p;
  }
  WAVE_FENCE();
#pragma unroll
  for (int t = 0; t < 4; ++t){
    int p = (t * 4 + sub) ^ ll;
    bf16x8 af = *(const bf16x8*)(Aw + ll * 128 + p * 8);
    const short* bb = Bp + (size_t)(t * 8) * 512 + l * 8;
#pragma unroll
    for (int nf = 0; nf < 8; ++nf){
      bf16x8 bq = *(const bf16x8*)(bb + nf * 512);
      acc[nf] = __builtin_amdgcn_mfma_f32_16x16x32_bf16(af, bq, acc[nf], 0, 0, 0);
    }
  }
  const int lr = l >> 4, lc = l & 15;
#pragma unroll
  for (int nf = 0; nf < 8; ++nf){
    int col = nf * 16 + lc;
    float bv = rb[col];
#pragma unroll
    for (int r = 0; r < 4; ++r){
      int row = mbase + w * 16 + lr * 4 + r;
      if (row < NN) resb[(size_t)row * 128 + col] = f2bf(acc[nf][r] + bv);
    }
  }
}

// ------- fused RGCN layer: per-wave agg -> LDS -> MFMA, 9 phases ----------
// out[v,:] = resb[v,:] + relu( [mean_r(h[src])..., h[v]] @ Bp + bias )
// OUTMODE 1: outb bf16 (layers 1,2); OUTMODE 2: outf fp32 (layer 3)
template<int OUTMODE>
__launch_bounds__(256, 4)
__global__ void fused_k(const u32* __restrict__ offs, const int* __restrict__ ssrc,
                        const unsigned short* __restrict__ h,
                        const short* __restrict__ Bp,
                        const float* __restrict__ bias,
                        const unsigned short* __restrict__ resb,
                        float* __restrict__ outf, unsigned short* __restrict__ outb){
  __shared__ short Alds[64 * 128];           // 16 KB; each wave owns a 16x128 slice
  const int tid = threadIdx.x;
  const int w = tid >> 6, l = tid & 63;
  const int sub = l >> 4, ll = l & 15;
  const int mbase = blockIdx.x * 64;
  short* Aw = Alds + w * 16 * 128;
  f32x4 acc[8] = {};

#pragma unroll 1
  for (int kt = 0; kt < 9; ++kt){
    if (kt < 8){
      // aggregate this wave's 16 segments for relation kt, 4 concurrent
#pragma unroll 1
      for (int it = 0; it < 4; ++it){
        int rloc = it * 4 + sub;
        int v = mbase + w * 16 + rloc; if (v > NN - 1) v = NN - 1;
        u32 beg = offs[(size_t)kt * NN + v], end = offs[(size_t)kt * NN + v + 1];
        float s[8] = {0.f,0.f,0.f,0.f,0.f,0.f,0.f,0.f};
        const unsigned short* hb = h + (size_t)ll * 8;
        u32 e = beg;
        for (; e + 2 <= end; e += 2){
          int s0 = ssrc[e], s1 = ssrc[e + 1];
          u32x4 p0 = *(const u32x4*)(hb + (size_t)s0 * 128);
          u32x4 p1 = *(const u32x4*)(hb + (size_t)s1 * 128);
#pragma unroll
          for (int i = 0; i < 4; ++i){
            s[2*i]   += __uint_as_float(p0[i] << 16)         + __uint_as_float(p1[i] << 16);
            s[2*i+1] += __uint_as_float(p0[i] & 0xffff0000u) + __uint_as_float(p1[i] & 0xffff0000u);
          }
        }
        if (e < end){
          int s0 = ssrc[e];
          u32x4 p0 = *(const u32x4*)(hb + (size_t)s0 * 128);
#pragma unroll
          for (int i = 0; i < 4; ++i){
            s[2*i]   += __uint_as_float(p0[i] << 16);
            s[2*i+1] += __uint_as_float(p0[i] & 0xffff0000u);
          }
        }
        u32 deg = end - beg;
        if (deg){
          float inv = 1.f / (float)deg;
#pragma unroll
          for (int i = 0; i < 8; ++i) s[i] *= inv;
        }
        u32x4 o;
#pragma unroll
        for (int i = 0; i < 4; ++i)
          o[i] = (u32)f2bf(s[2*i]) | ((u32)f2bf(s[2*i+1]) << 16);
        *(u32x4*)(Aw + rloc * 128 + ((ll ^ rloc) << 3)) = o;
      }
    } else {
      // root phase: A = h rows
#pragma unroll
      for (int j = 0; j < 4; ++j){
        int rloc = j * 4 + sub;
        int v = mbase + w * 16 + rloc; if (v > NN - 1) v = NN - 1;
        u32x4 p = *(const u32x4*)(h + (size_t)v * 128 + ll * 8);
        *(u32x4*)(Aw + rloc * 128 + ((ll ^ rloc) << 3)) = p;
      }
    }
    WAVE_FENCE();
#pragma unroll
    for (int t = 0; t < 4; ++t){
      int p = (t * 4 + sub) ^ ll;
      bf16x8 af = *(const bf16x8*)(Aw + ll * 128 + p * 8);
      const short* bb = Bp + (size_t)(((size_t)kt * 4 + t) * 8) * 512 + l * 8;
#pragma unroll
      for (int nf = 0; nf < 8; ++nf){
        bf16x8 bq = *(const bf16x8*)(bb + nf * 512);
        acc[nf] = __builtin_amdgcn_mfma_f32_16x16x32_bf16(af, bq, acc[nf], 0, 0, 0);
      }
    }
    WAVE_FENCE();
  }

  const int lr = l >> 4, lc = l & 15;
#pragma unroll
  for (int nf = 0; nf < 8; ++nf){
    int col = nf * 16 + lc;
    float bv = bias[col];
#pragma unroll
    for (int r = 0; r < 4; ++r){
      int row = mbase + w * 16 + lr * 4 + r;
      if (row < NN){
        float v = acc[nf][r] + bv;
        v = bf2f(resb[(size_t)row * 128 + col]) + fmaxf(v, 0.f);
        if (OUTMODE == 1) outb[(size_t)row * 128 + col] = f2bf(v);
        else              outf[(size_t)row * 128 + col] = v;
      }
    }
  }
}

extern "C" void kernel_launch(void* const* d_in, const int* in_sizes, int n_in,
                              void* d_out, int out_size, void* d_ws, size_t ws_size,
                              hipStream_t stream){
  const float* x  = (const float*)d_in[0];
  const int*   ei = (const int*)d_in[1];
  const int*   et = (const int*)d_in[2];
  const float* W1 = (const float*)d_in[3];
  const float* r1 = (const float*)d_in[4];
  const float* b1 = (const float*)d_in[5];
  const float* W2 = (const float*)d_in[6];
  const float* r2 = (const float*)d_in[7];
  const float* b2 = (const float*)d_in[8];
  const float* W3 = (const float*)d_in[9];
  const float* r3 = (const float*)d_in[10];
  const float* b3 = (const float*)d_in[11];
  const float* rw = (const float*)d_in[12];
  const float* rb = (const float*)d_in[13];
  const int* srcv = ei;
  const int* dstv = ei + EE;

  char* p = (char*)d_ws;
  auto take = [&](size_t b)->char*{ char* q = p; p += (b + 255) & ~(size_t)255; return q; };
  unsigned short* xb   = (unsigned short*)take((size_t)NN * 128 * 2);
  unsigned short* h1   = (unsigned short*)take((size_t)NN * 128 * 2);
  unsigned short* h2   = (unsigned short*)take((size_t)NN * 128 * 2);
  unsigned short* resb = (unsigned short*)take((size_t)NN * 128 * 2);
  short* Bp1 = (short*)take(36 * 4096 * 2);
  short* Bp2 = (short*)take(36 * 4096 * 2);
  short* Bp3 = (short*)take(36 * 4096 * 2);
  short* BpR = (short*)take(4 * 4096 * 2);
  u32* cnt  = (u32*)take((size_t)NSEG * 4);
  u32* offs = (u32*)take((size_t)(NSEG + 1) * 4);
  u32* cur  = (u32*)take((size_t)NSEG * 4);
  int* ssrc = (int*)take((size_t)EE * 4);
  u32* bsum = (u32*)take((size_t)NB_SCAN * 4);

  hipMemsetAsync(cnt, 0, (size_t)NSEG * 4, stream);
  hipMemsetAsync(cur, 0, (size_t)NSEG * 4, stream);

  // conversions + weight packing (once)
  cvt_k<<<(NN * 128 / 4 + 255) / 256, 256, 0, stream>>>(x, xb, NN * 128 / 4);
  pack_k<<<(36 * 512 + 255) / 256, 256, 0, stream>>>(W1, r1, Bp1, 36, 1024);
  pack_k<<<(36 * 512 + 255) / 256, 256, 0, stream>>>(W2, r2, Bp2, 36, 1024);
  pack_k<<<(36 * 512 + 255) / 256, 256, 0, stream>>>(W3, r3, Bp3, 36, 1024);
  pack_k<<<(4 * 512 + 255) / 256, 256, 0, stream>>>(nullptr, rw, BpR, 4, 0);

  // CSR over segments (etype*NN + dst), once for all layers
  count_k<<<(EE + 255) / 256, 256, 0, stream>>>(dstv, et, cnt);
  scan1_k<<<NB_SCAN, 256, 0, stream>>>(cnt, offs, bsum);
  scan2_k<<<1, 512, 0, stream>>>(bsum);
  scan3_k<<<NB_SCAN, 256, 0, stream>>>(offs, bsum);
  fill_k<<<(EE + 255) / 256, 256, 0, stream>>>(srcv, dstv, et, offs, cur, ssrc);

  const int GB = (NN + 63) / 64;  // 782

  // res = bf16(x @ res_w + res_b)
  resg_k<<<GB, 256, 0, stream>>>(xb, BpR, rb, resb);

  // fused layers
  fused_k<1><<<GB, 256, 0, stream>>>(offs, ssrc, xb, Bp1, b1, resb, nullptr, h1);
  fused_k<1><<<GB, 256, 0, stream>>>(offs, ssrc, h1, Bp2, b2, resb, nullptr, h2);
  fused_k<2><<<GB, 256, 0, stream>>>(offs, ssrc, h2, Bp3, b3, resb, (float*)d_out, nullptr);
}